// Round 7
// baseline (639.409 us; speedup 1.0000x reference)
//
#include <hip/hip_runtime.h>
#include <math.h>

#define HEAD 128
typedef _Float16 f16;
typedef _Float16 f16x8 __attribute__((ext_vector_type(8)));
typedef float f32x4 __attribute__((ext_vector_type(4)));

// ---------------- compile-time Möbius band table ----------------
constexpr int mu_of(int n) {
  int m = n, cnt = 0;
  for (int p = 2; p * p <= m; ++p) {
    if (m % p == 0) {
      m /= p; ++cnt;
      if (m % p == 0) return 0;
    }
  }
  if (m > 1) ++cnt;
  return (cnt & 1) ? -1 : 1;
}
constexpr int key_of(int idx) {
  int mu = mu_of(idx + 1);
  return mu == 1 ? 0 : (mu == 0 ? 1 : 2);
}
struct Tbl {
  int band[HEAD];
  float qm[HEAD];
};
constexpr Tbl make_tbl() {
  Tbl t{};
  constexpr float qv[4] = {15.f, 7.f, 7.f, 3.f};
  for (int p = 0; p < HEAD; ++p) {
    int kp = key_of(p);
    int rank = 0;
    for (int j = 0; j < HEAD; ++j) {
      int kj = key_of(j);
      if (kj < kp || (kj == kp && j < p)) ++rank;
    }
    t.band[p] = rank >> 5;
    t.qm[p] = qv[rank >> 5];
  }
  return t;
}
__constant__ Tbl g_tbl = make_tbl();

// ------- fused f32 -> (hi,lo) f16 split for x and W, pre-scaled by 64 ------
__global__ __launch_bounds__(256) void split_all(
    const float* __restrict__ x, const float* __restrict__ W,
    f16* __restrict__ xh, f16* __restrict__ xl,
    f16* __restrict__ wh, f16* __restrict__ wl,
    long n8x, long n8tot) {
  long i = blockIdx.x * (long)blockDim.x + threadIdx.x;
  long stride = (long)gridDim.x * blockDim.x;
  for (; i < n8tot; i += stride) {
    const float* s;
    f16 *h, *l;
    long j;
    if (i < n8x) {
      s = x; h = xh; l = xl; j = i;
    } else {
      s = W; h = wh; l = wl; j = i - n8x;
    }
    const float4* p = (const float4*)s + 2 * j;
    float4 a = p[0], c = p[1];
    float v[8] = {a.x, a.y, a.z, a.w, c.x, c.y, c.z, c.w};
    f16x8 hv, lv;
#pragma unroll
    for (int t = 0; t < 8; ++t) {
      float sv = v[t] * 64.f;
      f16 ht = (f16)sv;
      hv[t] = ht;
      lv[t] = (f16)(sv - (float)ht);
    }
    ((f16x8*)h)[j] = hv;
    ((f16x8*)l)[j] = lv;
  }
}

// ---------------- MFMA GEMM, LDS-free register pipeline --------------------
// C[M,N] = (Ah+Al)(Bh+Bl)^T /4096 + bias, AlBl dropped.
// 1 wave/block, 64x64 tile, BK=32. A/B frag of mfma_f32_16x16x32_f16 for
// lane (frow=lane&15, kq=lane>>4) is the contiguous 16B global chunk at
// row (tile + s*16 + frow), cols kq*8..kq*8+7  ->  load fragments DIRECTLY
// from global (dwordx4), double-buffered in registers. No LDS, no barriers,
// no vmcnt(0) drain: loads of k+1 fly behind the 48 MFMAs of k.
__global__ __launch_bounds__(64) void gemm_direct(
    const f16* __restrict__ Ah, const f16* __restrict__ Al,
    const f16* __restrict__ Bh, const f16* __restrict__ Bl,
    const float* __restrict__ bias, float* __restrict__ C,
    int M, int N, int K) {
  const int lane = threadIdx.x;
  const int m0 = blockIdx.x * 64;
  const int n0 = blockIdx.y * 64;
  const int frow = lane & 15;
  const int kq = lane >> 4;                 // 0..3
  const size_t loff = (size_t)frow * K + kq * 8;  // per-lane elem offset

  f32x4 acc[4][4];
#pragma unroll
  for (int i = 0; i < 4; ++i)
#pragma unroll
    for (int j = 0; j < 4; ++j) acc[i][j] = (f32x4){0.f, 0.f, 0.f, 0.f};

  f16x8 a0[2][4], b0[2][4], a1[2][4], b1[2][4];

  // uniform-base + divergent-offset form so the compiler emits saddr loads
#define LOADF(AB, BB, it)                                                  \
  do {                                                                     \
    const size_t ko = (size_t)(it) * 32 + loff;                            \
    _Pragma("unroll") for (int s = 0; s < 4; ++s) {                        \
      AB[0][s] = *(const f16x8*)(Ah + (size_t)(m0 + s * 16) * K + ko);     \
      AB[1][s] = *(const f16x8*)(Al + (size_t)(m0 + s * 16) * K + ko);     \
      BB[0][s] = *(const f16x8*)(Bh + (size_t)(n0 + s * 16) * K + ko);     \
      BB[1][s] = *(const f16x8*)(Bl + (size_t)(n0 + s * 16) * K + ko);     \
    }                                                                      \
  } while (0)

#define MFMAS(AB, BB)                                                      \
  do {                                                                     \
    _Pragma("unroll") for (int i = 0; i < 4; ++i)                          \
        _Pragma("unroll") for (int j = 0; j < 4; ++j) {                    \
      acc[i][j] = __builtin_amdgcn_mfma_f32_16x16x32_f16(AB[0][i], BB[0][j], acc[i][j], 0, 0, 0); \
      acc[i][j] = __builtin_amdgcn_mfma_f32_16x16x32_f16(AB[1][i], BB[0][j], acc[i][j], 0, 0, 0); \
      acc[i][j] = __builtin_amdgcn_mfma_f32_16x16x32_f16(AB[0][i], BB[1][j], acc[i][j], 0, 0, 0); \
    }                                                                      \
  } while (0)

  const int nIter = K / 32;  // 160 (even)
  LOADF(a0, b0, 0);
  for (int it = 0; it < nIter; it += 2) {
    LOADF(a1, b1, it + 1);      // it+1 <= nIter-1 always (nIter even)
    MFMAS(a0, b0);
    if (it + 2 < nIter) LOADF(a0, b0, it + 2);
    MFMAS(a1, b1);
  }

  // epilogue: C/D layout col=lane&15, row=(lane>>4)*4+r
  const float inv = 1.f / 4096.f;
#pragma unroll
  for (int j = 0; j < 4; ++j) {
    const int col = n0 + j * 16 + frow;
    const float bv = bias[col];
#pragma unroll
    for (int i = 0; i < 4; ++i) {
#pragma unroll
      for (int r = 0; r < 4; ++r) {
        const int row = m0 + i * 16 + kq * 4 + r;
        C[(size_t)row * N + col] = acc[i][j][r] * inv + bv;
      }
    }
  }
#undef LOADF
#undef MFMAS
}

// ---------------- fallback fp32 GEMM (proven) ----------------
#define BM 128
#define BN 64
#define BKK 8
#define TM 8
#define TN 4

__global__ __launch_bounds__(256) void sgemm_nt(
    const float* __restrict__ A, const float* __restrict__ B,
    const float* __restrict__ bias, float* __restrict__ C,
    int M, int N, int K) {
  __shared__ float As[BKK][BM];
  __shared__ float Bs[BKK][BN];

  const int tid = threadIdx.x;
  const int tn = tid & 15;
  const int tm = tid >> 4;
  const int bx = blockIdx.x;
  const int by = blockIdx.y;

  const float* Ab = A + (size_t)by * BM * K;
  const float* Bb = B + (size_t)bx * BN * K;

  const int ar = tid >> 1;
  const int ak = (tid & 1) * 4;

  float acc[TM][TN];
#pragma unroll
  for (int i = 0; i < TM; ++i)
#pragma unroll
    for (int j = 0; j < TN; ++j) acc[i][j] = 0.f;

  for (int k0 = 0; k0 < K; k0 += BKK) {
    float4 av = *(const float4*)(Ab + (size_t)ar * K + k0 + ak);
    float4 bv = make_float4(0.f, 0.f, 0.f, 0.f);
    if (tid < 128) bv = *(const float4*)(Bb + (size_t)ar * K + k0 + ak);

    __syncthreads();
    As[ak + 0][ar] = av.x;
    As[ak + 1][ar] = av.y;
    As[ak + 2][ar] = av.z;
    As[ak + 3][ar] = av.w;
    if (tid < 128) {
      Bs[ak + 0][ar] = bv.x;
      Bs[ak + 1][ar] = bv.y;
      Bs[ak + 2][ar] = bv.z;
      Bs[ak + 3][ar] = bv.w;
    }
    __syncthreads();

#pragma unroll
    for (int kk = 0; kk < BKK; ++kk) {
      float a[TM], b[TN];
#pragma unroll
      for (int i = 0; i < TM; ++i) a[i] = As[kk][tm * TM + i];
#pragma unroll
      for (int j = 0; j < TN; ++j) b[j] = Bs[kk][tn * TN + j];
#pragma unroll
      for (int i = 0; i < TM; ++i)
#pragma unroll
        for (int j = 0; j < TN; ++j) acc[i][j] += a[i] * b[j];
    }
  }

  const int row0 = by * BM + tm * TM;
  const int col0 = bx * BN + tn * TN;
  float bj[TN];
#pragma unroll
  for (int j = 0; j < TN; ++j) bj[j] = bias[col0 + j];
#pragma unroll
  for (int i = 0; i < TM; ++i) {
    float4 v = make_float4(acc[i][0] + bj[0], acc[i][1] + bj[1],
                           acc[i][2] + bj[2], acc[i][3] + bj[3]);
    *(float4*)(C + (size_t)(row0 + i) * N + col0) = v;
  }
}

// ---------------- Hadamard + banded quant-dequant + inverse ----------------
__device__ inline void fwht2(float& e0, float& e1, int lane) {
  float a = e0 + e1;
  float b = e0 - e1;
  e0 = a;
  e1 = b;
#pragma unroll
  for (int s = 1; s <= 32; s <<= 1) {
    float p0 = __shfl_xor(e0, s);
    float p1 = __shfl_xor(e1, s);
    bool up = (lane & s) != 0;
    e0 = up ? (p0 - e0) : (e0 + p0);
    e1 = up ? (p1 - e1) : (e1 + p1);
  }
}

__global__ __launch_bounds__(256) void hadq(const float* __restrict__ Y,
                                            float* __restrict__ O, int nrows) {
  const int lane = threadIdx.x & 63;
  const int wave = (blockIdx.x * (blockDim.x >> 6)) + (threadIdx.x >> 6);
  const int nwaves = gridDim.x * (blockDim.x >> 6);

  const int b0 = g_tbl.band[lane];
  const int b1 = g_tbl.band[lane + 64];
  const float qm0 = g_tbl.qm[lane];
  const float qm1 = g_tbl.qm[lane + 64];

  for (int row = wave; row < nrows; row += nwaves) {
    const float* y = Y + (size_t)row * HEAD;
    float e0 = y[lane];
    float e1 = y[lane + 64];

    fwht2(e0, e1, lane);

    float f0 = fabsf(e0), f1 = fabsf(e1);
    float ab0 = fmaxf(b0 == 0 ? f0 : 0.f, b1 == 0 ? f1 : 0.f);
    float ab1 = fmaxf(b0 == 1 ? f0 : 0.f, b1 == 1 ? f1 : 0.f);
    float ab2 = fmaxf(b0 == 2 ? f0 : 0.f, b1 == 2 ? f1 : 0.f);
    float ab3 = fmaxf(b0 == 3 ? f0 : 0.f, b1 == 3 ? f1 : 0.f);
#pragma unroll
    for (int s = 32; s >= 1; s >>= 1) {
      ab0 = fmaxf(ab0, __shfl_xor(ab0, s));
      ab1 = fmaxf(ab1, __shfl_xor(ab1, s));
      ab2 = fmaxf(ab2, __shfl_xor(ab2, s));
      ab3 = fmaxf(ab3, __shfl_xor(ab3, s));
    }
    float am0 = b0 == 0 ? ab0 : (b0 == 1 ? ab1 : (b0 == 2 ? ab2 : ab3));
    float am1 = b1 == 0 ? ab0 : (b1 == 1 ? ab1 : (b1 == 2 ? ab2 : ab3));

    float s0 = am0 > 0.f ? am0 / qm0 : 1.0f;
    float s1 = am1 > 0.f ? am1 / qm1 : 1.0f;

    float q0 = fminf(fmaxf(rintf(e0 / s0), -qm0), qm0);
    float q1 = fminf(fmaxf(rintf(e1 / s1), -qm1), qm1);
    e0 = q0 * s0;
    e1 = q1 * s1;

    fwht2(e0, e1, lane);
    float r0 = e0 * 0.0078125f;
    float r1 = e1 * 0.0078125f;
    if (r0 != r0) r0 = 0.f;
    if (r1 != r1) r1 = 0.f;
    r0 = fminf(fmaxf(r0, -65504.f), 65504.f);
    r1 = fminf(fmaxf(r1, -65504.f), 65504.f);

    float* o = O + (size_t)row * HEAD;
    o[lane] = r0;
    o[lane + 64] = r1;
  }
}

// ---------------- launch ----------------
extern "C" void kernel_launch(void* const* d_in, const int* in_sizes, int n_in,
                              void* d_out, int out_size, void* d_ws, size_t ws_size,
                              hipStream_t stream) {
  const float* x = (const float*)d_in[0];
  const float* W = (const float*)d_in[1];
  const float* b = (const float*)d_in[2];
  float* out = (float*)d_out;

  const int N = in_sizes[2];      // 5120
  const int K = N;                // 5120
  const int M = in_sizes[0] / K;  // 1024

  const size_t MK = (size_t)M * K;
  const size_t NK = (size_t)N * K;
  const size_t need = (MK + NK) * 2 * sizeof(f16);  // hi+lo for x and W

  if (ws_size >= need) {
    f16* xh = (f16*)d_ws;
    f16* xl = xh + MK;
    f16* wh = xl + MK;
    f16* wl = wh + NK;

    const long n8x = (long)(MK / 8);
    const long n8tot = (long)((MK + NK) / 8);
    split_all<<<4096, 256, 0, stream>>>(x, W, xh, xl, wh, wl, n8x, n8tot);

    dim3 grid(M / 64, N / 64);  // 16 x 80 = 1280 blocks
    gemm_direct<<<grid, 64, 0, stream>>>(xh, xl, wh, wl, b, out, M, N, K);
  } else {
    dim3 grid(N / BN, M / BM);
    sgemm_nt<<<grid, 256, 0, stream>>>(x, W, b, out, M, N, K);
  }

  const int nrows = out_size / HEAD;
  hadq<<<512, 256, 0, stream>>>(out, out, nrows);
}